// Round 3
// baseline (43.604 us; speedup 1.0000x reference)
//
#include <hip/hip_runtime.h>
#include <math.h>

#define HID 512
#define EMB 1024
#define N1 1536
#define N2 256

typedef __attribute__((ext_vector_type(8))) __bf16 bf16x8;
typedef __attribute__((ext_vector_type(4))) float fx4;

// ---------------- ws layout (bytes) ----------------
#define OFF_INPB 0          // [384][512] bf16 = 393216
#define OFF_P2   393216     // [4][128][256] f32 = 524288
#define OFF_SC   917504     // [256] f32
#define OFF_SH   918528     // [256] f32

__device__ __forceinline__ fx4 mfma16(bf16x8 a, bf16x8 b, fx4 c) {
    return __builtin_amdgcn_mfma_f32_16x16x32_bf16(a, b, c, 0, 0, 0);
}

// LDS tile [64 rows][64 k] bf16; 16B granule g of row r -> physical g ^ (r&7).
__device__ __forceinline__ int lds_idx(int row, int g) {
    return row * 64 + ((g ^ (row & 7)) * 8);
}

__device__ __forceinline__ bf16x8 cvt8(float4 a, float4 b) {
    bf16x8 r;
    r[0] = (__bf16)a.x; r[1] = (__bf16)a.y; r[2] = (__bf16)a.z; r[3] = (__bf16)a.w;
    r[4] = (__bf16)b.x; r[5] = (__bf16)b.y; r[6] = (__bf16)b.z; r[7] = (__bf16)b.w;
    return r;
}

// ================= kG1: gather + convert + GEMM1 + epilogue =================
// inp_bf[m][n] = dot(emb[sample[b][s]], t_w[n]) + t_b[n] (+ p_feature[u/v][n])
// with m = s*128+b.  grid (8 n-tiles, 6 m-tiles), 256 threads (4 waves 32x32).
__global__ __launch_bounds__(256)
void kG1(const int* __restrict__ sample, const int* __restrict__ gb, int n_nodes,
         const float* __restrict__ p_feature,
         const float* __restrict__ tweet_emb, const float* __restrict__ desc_emb,
         const float* __restrict__ t_w, const float* __restrict__ t_b,
         __bf16* __restrict__ inp_bf)
{
    const int n0 = blockIdx.x * 64;
    const int m0 = blockIdx.y * 64;
    const int s  = m0 >> 7;           // 0,1,2 (64 | m0, tiles never cross s)
    const int b0 = m0 & 127;
    const int t  = threadIdx.x;
    const int wid = t >> 6, l = t & 63;
    const int mbase = (wid >> 1) * 32, nbase = (wid & 1) * 32;

    __shared__ __bf16 Alds[64 * 64];
    __shared__ __bf16 Blds[64 * 64];
    __shared__ int node_lds[64];

    // u_idx scan: first node of each graph (only needed for s != 1)
    if (s != 1) {
        for (int n = t; n < n_nodes; n += 256) {
            const int g = gb[n];
            const int rel = g - b0;
            if (rel >= 0 && rel < 64) {
                if (n == 0 || gb[n - 1] != g) node_lds[rel] = n;
            }
        }
    }

    const int srow = t >> 2;          // staging row 0..63
    const int c0   = (t & 3) * 16;    // f32 col offset within 64-k tile
    const int g0   = (t & 3) * 2;     // LDS granule pair

    const int bb  = b0 + srow;        // graph index of staged A row
    const int sid = sample[bb * 3 + s];
    const float* erow = ((s == 1) ? tweet_emb : desc_emb) + (size_t)sid * EMB;
    const float* wrow = t_w + (size_t)(n0 + srow) * EMB;

    fx4 acc[2][2] = {};

    float4 pa0, pa1, pa2, pa3, pb0, pb1, pb2, pb3;
    {
        const float* a = erow + c0;
        const float* b = wrow + c0;
        pa0 = *(const float4*)(a);      pa1 = *(const float4*)(a + 4);
        pa2 = *(const float4*)(a + 8);  pa3 = *(const float4*)(a + 12);
        pb0 = *(const float4*)(b);      pb1 = *(const float4*)(b + 4);
        pb2 = *(const float4*)(b + 8);  pb3 = *(const float4*)(b + 12);
    }

    for (int kt = 0; kt < 16; ++kt) {
        bf16x8 av0 = cvt8(pa0, pa1), av1 = cvt8(pa2, pa3);
        bf16x8 bv0 = cvt8(pb0, pb1), bv1 = cvt8(pb2, pb3);
        __syncthreads();
        *(bf16x8*)&Alds[lds_idx(srow, g0)]     = av0;
        *(bf16x8*)&Alds[lds_idx(srow, g0 + 1)] = av1;
        *(bf16x8*)&Blds[lds_idx(srow, g0)]     = bv0;
        *(bf16x8*)&Blds[lds_idx(srow, g0 + 1)] = bv1;
        __syncthreads();

        if (kt < 15) {
            const float* a = erow + (kt + 1) * 64 + c0;
            const float* b = wrow + (kt + 1) * 64 + c0;
            pa0 = *(const float4*)(a);      pa1 = *(const float4*)(a + 4);
            pa2 = *(const float4*)(a + 8);  pa3 = *(const float4*)(a + 12);
            pb0 = *(const float4*)(b);      pb1 = *(const float4*)(b + 4);
            pb2 = *(const float4*)(b + 8);  pb3 = *(const float4*)(b + 12);
        }

        #pragma unroll
        for (int kq = 0; kq < 2; ++kq) {
            const int g = kq * 4 + (l >> 4);
            bf16x8 a0 = *(const bf16x8*)&Alds[lds_idx(mbase +      (l & 15), g)];
            bf16x8 a1 = *(const bf16x8*)&Alds[lds_idx(mbase + 16 + (l & 15), g)];
            bf16x8 b0 = *(const bf16x8*)&Blds[lds_idx(nbase +      (l & 15), g)];
            bf16x8 b1 = *(const bf16x8*)&Blds[lds_idx(nbase + 16 + (l & 15), g)];
            acc[0][0] = mfma16(a0, b0, acc[0][0]);
            acc[0][1] = mfma16(a0, b1, acc[0][1]);
            acc[1][0] = mfma16(a1, b0, acc[1][0]);
            acc[1][1] = mfma16(a1, b1, acc[1][1]);
        }
    }

    const int addv = (s == 2) ? 1 : 0;
    #pragma unroll
    for (int mi = 0; mi < 2; ++mi)
        #pragma unroll
        for (int ni = 0; ni < 2; ++ni) {
            const int row = m0 + mbase + mi * 16 + (l >> 4) * 4;
            const int col = n0 + nbase + ni * 16 + (l & 15);
            const float tb = t_b[col];
            #pragma unroll
            for (int j = 0; j < 4; ++j) {
                const int r = row + j;
                float v = acc[mi][ni][j] + tb;
                if (s != 1) {
                    const int node = node_lds[r - m0] + addv;
                    v += p_feature[(size_t)node * HID + col];
                }
                inp_bf[(size_t)r * HID + col] = (__bf16)v;
            }
        }
}

// ================= kG2: GEMM2 (split-K=4), inline w1 f32->bf16 =================
// part2[ks][b][n] = inp[b][kslice] . w1[n][kslice]
// inp logical [128][1536]; physical inp_bf[(k>>9)*128 + b][k&511].
// grid (4 n-tiles, 2 m-tiles, 4 ks), 256 threads.
__global__ __launch_bounds__(256)
void kG2(const __bf16* __restrict__ inp_bf, const float* __restrict__ w1,
         float* __restrict__ part2)
{
    const int n0 = blockIdx.x * 64;
    const int m0 = blockIdx.y * 64;
    const int ks = blockIdx.z;
    const int t  = threadIdx.x;
    const int wid = t >> 6, l = t & 63;
    const int mbase = (wid >> 1) * 32, nbase = (wid & 1) * 32;

    __shared__ __bf16 Alds[64 * 64];
    __shared__ __bf16 Blds[64 * 64];

    const int srow = t >> 2;
    const int c0   = (t & 3) * 16;
    const int g0   = (t & 3) * 2;

    const float* wrow = w1 + (size_t)(n0 + srow) * N1;

    fx4 acc[2][2] = {};

    bf16x8 av0, av1;
    float4 pb0, pb1, pb2, pb3;
    {
        const int k0 = ks * 384;
        const __bf16* ap = inp_bf + (size_t)(((k0 >> 9) * 128) + m0 + srow) * HID + (k0 & 511) + c0;
        av0 = *(const bf16x8*)ap; av1 = *(const bf16x8*)(ap + 8);
        const float* b = wrow + k0 + c0;
        pb0 = *(const float4*)(b);      pb1 = *(const float4*)(b + 4);
        pb2 = *(const float4*)(b + 8);  pb3 = *(const float4*)(b + 12);
    }

    for (int kt = 0; kt < 6; ++kt) {
        bf16x8 bv0 = cvt8(pb0, pb1), bv1 = cvt8(pb2, pb3);
        __syncthreads();
        *(bf16x8*)&Alds[lds_idx(srow, g0)]     = av0;
        *(bf16x8*)&Alds[lds_idx(srow, g0 + 1)] = av1;
        *(bf16x8*)&Blds[lds_idx(srow, g0)]     = bv0;
        *(bf16x8*)&Blds[lds_idx(srow, g0 + 1)] = bv1;
        __syncthreads();

        if (kt < 5) {
            const int k0 = ks * 384 + (kt + 1) * 64;
            const __bf16* ap = inp_bf + (size_t)(((k0 >> 9) * 128) + m0 + srow) * HID + (k0 & 511) + c0;
            av0 = *(const bf16x8*)ap; av1 = *(const bf16x8*)(ap + 8);
            const float* b = wrow + k0 + c0;
            pb0 = *(const float4*)(b);      pb1 = *(const float4*)(b + 4);
            pb2 = *(const float4*)(b + 8);  pb3 = *(const float4*)(b + 12);
        }

        #pragma unroll
        for (int kq = 0; kq < 2; ++kq) {
            const int g = kq * 4 + (l >> 4);
            bf16x8 a0 = *(const bf16x8*)&Alds[lds_idx(mbase +      (l & 15), g)];
            bf16x8 a1 = *(const bf16x8*)&Alds[lds_idx(mbase + 16 + (l & 15), g)];
            bf16x8 b0 = *(const bf16x8*)&Blds[lds_idx(nbase +      (l & 15), g)];
            bf16x8 b1 = *(const bf16x8*)&Blds[lds_idx(nbase + 16 + (l & 15), g)];
            acc[0][0] = mfma16(a0, b0, acc[0][0]);
            acc[0][1] = mfma16(a0, b1, acc[0][1]);
            acc[1][0] = mfma16(a1, b0, acc[1][0]);
            acc[1][1] = mfma16(a1, b1, acc[1][1]);
        }
    }

    float* dst = part2 + (size_t)ks * (128 * 256);
    #pragma unroll
    for (int mi = 0; mi < 2; ++mi)
        #pragma unroll
        for (int ni = 0; ni < 2; ++ni) {
            const int row = m0 + mbase + mi * 16 + (l >> 4) * 4;
            const int col = n0 + nbase + ni * 16 + (l & 15);
            #pragma unroll
            for (int j = 0; j < 4; ++j)
                dst[(size_t)(row + j) * N2 + col] = acc[mi][ni][j];
        }
}

// ================= kS: BN batch stats -> scale/shift (no hbuf) =================
__global__ __launch_bounds__(256)
void kS(const float* __restrict__ part2, const float* __restrict__ b1,
        const float* __restrict__ gamma, const float* __restrict__ beta,
        float* __restrict__ scale, float* __restrict__ shift)
{
    const int bl = blockIdx.x;
    const int t  = threadIdx.x;
    const int j  = bl * 32 + (t & 31);
    const int q  = t >> 5;

    const float bias = b1[j];
    float sum = 0.f, sq = 0.f;
    for (int i = 0; i < 16; ++i) {
        const int b = q * 16 + i;
        float v = bias;
        #pragma unroll
        for (int p = 0; p < 4; ++p)
            v += part2[(size_t)p * (128 * 256) + b * N2 + j];
        sum += v;
        sq  += v * v;
    }

    __shared__ float s_sum[8][32];
    __shared__ float s_sq[8][32];
    s_sum[q][t & 31] = sum;
    s_sq[q][t & 31]  = sq;
    __syncthreads();

    if (t < 32) {
        float S = 0.f, Q = 0.f;
        #pragma unroll
        for (int q2 = 0; q2 < 8; ++q2) { S += s_sum[q2][t]; Q += s_sq[q2][t]; }
        const float mu  = S * (1.0f / 128.0f);
        const float var = Q * (1.0f / 128.0f) - mu * mu;
        const float rs  = rsqrtf(var + 1e-5f);
        const int jj = bl * 32 + t;
        const float sc = gamma[jj] * rs;
        scale[jj] = sc;
        shift[jj] = beta[jj] - mu * sc;
    }
}

// ============ kO: recompute h + BN affine + ReLU + dot(w2) + sigmoid ============
__global__ __launch_bounds__(256)
void kO(const float* __restrict__ part2, const float* __restrict__ b1,
        const float* __restrict__ scale, const float* __restrict__ shift,
        const float* __restrict__ w2, const float* __restrict__ b2,
        float* __restrict__ out)
{
    const int t  = threadIdx.x;
    const int wv = t >> 6;
    const int l  = t & 63;
    const int b0 = blockIdx.x * 8 + wv * 2;

    #pragma unroll
    for (int rr = 0; rr < 2; ++rr) {
        const int b = b0 + rr;
        float acc = 0.f;
        #pragma unroll
        for (int i = 0; i < 4; ++i) {
            const int j = l + i * 64;
            float v = b1[j];                       // same order as kS
            #pragma unroll
            for (int p = 0; p < 4; ++p)
                v += part2[(size_t)p * (128 * 256) + b * N2 + j];
            float x = v * scale[j] + shift[j];
            x = fmaxf(x, 0.f);
            acc += x * w2[j];
        }
        #pragma unroll
        for (int off = 32; off; off >>= 1) acc += __shfl_xor(acc, off);
        if (l == 0) out[b] = 1.0f / (1.0f + expf(-(acc + b2[0])));
    }
}

extern "C" void kernel_launch(void* const* d_in, const int* in_sizes, int n_in,
                              void* d_out, int out_size, void* d_ws, size_t ws_size,
                              hipStream_t stream) {
    const int*   sample    = (const int*)  d_in[0];
    const int*   gb        = (const int*)  d_in[1];
    const float* p_feature = (const float*)d_in[2];
    const float* tweet_emb = (const float*)d_in[3];
    const float* desc_emb  = (const float*)d_in[4];
    const float* t_w       = (const float*)d_in[5];
    const float* t_b       = (const float*)d_in[6];
    const float* w1        = (const float*)d_in[7];
    const float* b1        = (const float*)d_in[8];
    const float* gamma     = (const float*)d_in[9];
    const float* beta      = (const float*)d_in[10];
    const float* w2        = (const float*)d_in[11];
    const float* b2        = (const float*)d_in[12];
    float* out = (float*)d_out;

    char* ws = (char*)d_ws;
    __bf16* inp_bf = (__bf16*)(ws + OFF_INPB);
    float*  part2  = (float*)(ws + OFF_P2);
    float*  scale  = (float*)(ws + OFF_SC);
    float*  shift  = (float*)(ws + OFF_SH);
    const int n_nodes = in_sizes[1];

    kG1<<<dim3(8, 6), 256, 0, stream>>>(sample, gb, n_nodes, p_feature,
                                        tweet_emb, desc_emb, t_w, t_b, inp_bf);
    kG2<<<dim3(4, 2, 4), 256, 0, stream>>>(inp_bf, w1, part2);
    kS<<<8, 256, 0, stream>>>(part2, b1, gamma, beta, scale, shift);
    kO<<<16, 256, 0, stream>>>(part2, b1, scale, shift, w2, b2, out);
}